// Round 6
// baseline (452.945 us; speedup 1.0000x reference)
//
#include <hip/hip_runtime.h>

#define N_NODES 50000
#define N_EDGES 800000
#define C_IN 128
#define C_HID 256
#define C_OUT 128
#define BN_EPS 1e-5f

typedef __bf16 v8bf __attribute__((ext_vector_type(8)));
typedef float f32x4 __attribute__((ext_vector_type(4)));

// ---------- bf16 helpers (round-to-nearest-even) ----------
static __device__ __forceinline__ unsigned short f2bf(float f) {
    unsigned int u = __float_as_uint(f);
    u += 0x7fffu + ((u >> 16) & 1u);
    return (unsigned short)(u >> 16);
}
static __device__ __forceinline__ float bf2f(unsigned short h) {
    return __uint_as_float((unsigned int)h << 16);
}
static __device__ __forceinline__ unsigned int pack2(float a, float b) {
    return (unsigned int)f2bf(a) | ((unsigned int)f2bf(b) << 16);
}
static __device__ __forceinline__ float lo2f(unsigned int u) { return __uint_as_float(u << 16); }
static __device__ __forceinline__ float hi2f(unsigned int u) { return __uint_as_float(u & 0xffff0000u); }

// ---------------- degree ----------------

__global__ __launch_bounds__(256) void k_deg(const int* __restrict__ dst, int* __restrict__ deg) {
    int e = blockIdx.x * 256 + threadIdx.x;
    if (e < N_EDGES) atomicAdd(&deg[dst[e]], 1);
}

// ---------------- CSR build ----------------

__global__ __launch_bounds__(512) void k_scan1(const int* __restrict__ deg, int* __restrict__ rs,
                                               int* __restrict__ partial, float* __restrict__ dis) {
    __shared__ int s[512];
    int t = threadIdx.x;
    int i = blockIdx.x * 512 + t;
    int v = (i < N_NODES) ? deg[i] : 0;
    if (i < N_NODES) dis[i] = rsqrtf((float)v + 1.0f);
    s[t] = v;
    __syncthreads();
    for (int off = 1; off < 512; off <<= 1) {
        int tv = (t >= off) ? s[t - off] : 0;
        __syncthreads();
        s[t] += tv;
        __syncthreads();
    }
    if (i < N_NODES) rs[i + 1] = s[t];
    if (t == 511) partial[blockIdx.x] = s[511];
}

// fused scan2+scan3: each block locally scans the <=128 partials (L2-hot), applies offset,
// and writes cur[] (cursor init for scatter).
__global__ __launch_bounds__(256) void k_scan23(int* __restrict__ rs, const int* __restrict__ partial,
                                                int* __restrict__ cur, int nb) {
    __shared__ int pre[128];
    __shared__ int wsum[2];
    int t = threadIdx.x;
    int lane = t & 63;
    int pv = 0, v = 0;
    if (t < 128) {
        pv = (t < nb) ? partial[t] : 0;
        v = pv;
#pragma unroll
        for (int off = 1; off < 64; off <<= 1) {
            int u = __shfl_up(v, off);
            if (lane >= off) v += u;
        }
        if (lane == 63) wsum[t >> 6] = v;
    }
    __syncthreads();
    if (t < 128) {
        if (t >= 64) v += wsum[0];
        pre[t] = v - pv;  // exclusive prefix of block partials
    }
    __syncthreads();
    int i = blockIdx.x * 256 + t;
    if (i < N_NODES) {
        int vv = rs[i + 1] + pre[i >> 9];
        rs[i + 1] = vv;
        cur[i + 1] = vv;
    }
    if (i == 0) { rs[0] = 0; cur[0] = 0; }
}

__global__ __launch_bounds__(256) void k_scatter(const int* __restrict__ src, const int* __restrict__ dst,
                                                 int* __restrict__ cur, int* __restrict__ eidx) {
    int e = blockIdx.x * 256 + threadIdx.x;
    if (e < N_EDGES) {
        int pos = atomicAdd(&cur[dst[e]], 1);
        eidx[pos] = src[e];
    }
}

// ---------------- weight transpose -> bf16 [n][k] ----------------

__global__ __launch_bounds__(256) void k_wtrans(const float* __restrict__ W1, const float* __restrict__ W2,
                                                unsigned short* __restrict__ WT1, unsigned short* __restrict__ WT2) {
    int i = blockIdx.x * 256 + threadIdx.x;
    if (i < C_IN * C_HID) {
        int n = i / C_IN, k = i - n * C_IN;
        WT1[n * C_IN + k] = f2bf(W1[k * C_HID + n]);
    } else {
        int j = i - C_IN * C_HID;
        if (j < C_HID * C_OUT) {
            int n = j / C_HID, k = j - n * C_HID;
            WT2[n * C_HID + k] = f2bf(W2[k * C_OUT + n]);
        }
    }
}

// ---------------- MFMA bf16 GEMM -> CHUNKED bf16 out ----------------
// C stored as Cc[chunk][row][32] (chunk = col/32) so the aggregation gathers 64B cachelines.
// TRANS: A is chunked bf16 z1c[chunk][row][32] with fused BN+ReLU.

#define GBM 128
#define GBK 64
#define LDA 72

template <bool TRANS>
__global__ __launch_bounds__(256) void k_gemm(const void* __restrict__ Av, const unsigned short* __restrict__ BT,
                                              unsigned short* __restrict__ Cc, const float* __restrict__ dis,
                                              const float* __restrict__ tsc, const float* __restrict__ tof,
                                              int M, int N, int K) {
    __shared__ unsigned short Alds[GBM * LDA];
    __shared__ unsigned short Blds[GBM * LDA];
    __shared__ float dis_s[GBM];

    int t = threadIdx.x;
    int row0 = blockIdx.x * GBM;
    int col0 = blockIdx.y * GBM;
    int wave = t >> 6, lane = t & 63;
    int wm = wave & 1, wn = wave >> 1;
    int lm = lane & 15, quad = lane >> 4;

    if (t < GBM) dis_s[t] = (row0 + t < M) ? dis[row0 + t] : 0.f;

    const float* Af = (const float*)Av;
    const unsigned short* Ah = (const unsigned short*)Av;

    int sr = t >> 1;
    int kb = (t & 1) * 32;

    f32x4 acc[4][4] = {};

    for (int kt = 0; kt < K; kt += GBK) {
        uint4 sa[4], sb[4];
        int r = row0 + sr;
#pragma unroll
        for (int j = 0; j < 4; ++j) {
            int k = kt + kb + 8 * j;
            if (TRANS) {
                // chunked A: z1c[chunk][r][32]; k..k+7 stays inside chunk k>>5
                uint4 h = (r < M) ? *(const uint4*)&Ah[((size_t)(k >> 5) * M + r) * 32 + (k & 31)]
                                  : make_uint4(0u, 0u, 0u, 0u);
                float4 s0 = *(const float4*)&tsc[k];
                float4 s1 = *(const float4*)&tsc[k + 4];
                float4 o0 = *(const float4*)&tof[k];
                float4 o1 = *(const float4*)&tof[k + 4];
                float f0 = fmaxf(fmaf(lo2f(h.x), s0.x, o0.x), 0.f);
                float f1 = fmaxf(fmaf(hi2f(h.x), s0.y, o0.y), 0.f);
                float f2 = fmaxf(fmaf(lo2f(h.y), s0.z, o0.z), 0.f);
                float f3 = fmaxf(fmaf(hi2f(h.y), s0.w, o0.w), 0.f);
                float f4 = fmaxf(fmaf(lo2f(h.z), s1.x, o1.x), 0.f);
                float f5 = fmaxf(fmaf(hi2f(h.z), s1.y, o1.y), 0.f);
                float f6 = fmaxf(fmaf(lo2f(h.w), s1.z, o1.z), 0.f);
                float f7 = fmaxf(fmaf(hi2f(h.w), s1.w, o1.w), 0.f);
                sa[j] = make_uint4(pack2(f0, f1), pack2(f2, f3), pack2(f4, f5), pack2(f6, f7));
            } else {
                float4 v0 = make_float4(0.f, 0.f, 0.f, 0.f), v1 = v0;
                if (r < M) {
                    v0 = *(const float4*)&Af[(size_t)r * K + k];
                    v1 = *(const float4*)&Af[(size_t)r * K + k + 4];
                }
                sa[j] = make_uint4(pack2(v0.x, v0.y), pack2(v0.z, v0.w),
                                   pack2(v1.x, v1.y), pack2(v1.z, v1.w));
            }
            sb[j] = *(const uint4*)&BT[(size_t)(col0 + sr) * K + k];
        }
        __syncthreads();
#pragma unroll
        for (int j = 0; j < 4; ++j) {
            *(uint4*)&Alds[sr * LDA + kb + 8 * j] = sa[j];
            *(uint4*)&Blds[sr * LDA + kb + 8 * j] = sb[j];
        }
        __syncthreads();
#pragma unroll
        for (int kc = 0; kc < 2; ++kc) {
            v8bf af[4], bfv[4];
#pragma unroll
            for (int im = 0; im < 4; ++im)
                af[im] = *(const v8bf*)&Alds[(wm * 64 + im * 16 + lm) * LDA + kc * 32 + quad * 8];
#pragma unroll
            for (int in = 0; in < 4; ++in)
                bfv[in] = *(const v8bf*)&Blds[(wn * 64 + in * 16 + lm) * LDA + kc * 32 + quad * 8];
#pragma unroll
            for (int im = 0; im < 4; ++im)
#pragma unroll
                for (int in = 0; in < 4; ++in)
                    acc[im][in] = __builtin_amdgcn_mfma_f32_16x16x32_bf16(af[im], bfv[in], acc[im][in], 0, 0, 0);
        }
    }
#pragma unroll
    for (int im = 0; im < 4; ++im) {
        int rb = wm * 64 + im * 16 + quad * 4;
#pragma unroll
        for (int in = 0; in < 4; ++in) {
            f32x4 c = acc[im][in];
            int col = col0 + wn * 64 + in * 16 + lm;
#pragma unroll
            for (int q = 0; q < 4; ++q) {
                int row = row0 + rb + q;
                if (row < M)
                    Cc[((size_t)(col >> 5) * M + row) * 32 + (col & 31)] = f2bf(c[q] * dis_s[rb + q]);
            }
        }
    }
}

// ---------------- chunked aggregation ----------------
// layer 1: 8 chunks of 32 channels; chunk = blockIdx.x & 7 (XCD swizzle -> 3.2MB strip / XCD L2).
// Wave: 16 lanes per edge (uint = 2 channels), 4 edges per gather instr, 8-edge unroll,
// shfl_xor(32/16) cross-slot reduce. One wave per node per chunk.

__global__ __launch_bounds__(256) void k_agg1(const unsigned short* __restrict__ g1c, const float* __restrict__ dis,
                                              const float* __restrict__ b1, const int* __restrict__ rs,
                                              const int* __restrict__ eidx, unsigned short* __restrict__ z1c) {
    int bx = blockIdx.x;
    int chunk = bx & 7;
    int grp = bx >> 3;
    int t = threadIdx.x;
    int wave = t >> 6, lane = t & 63;
    int wid = grp * 4 + wave;
    if (wid >= N_NODES) return;
    int slot = lane >> 4;   // 0..3 : edge slot
    int cp = lane & 15;     // channel-pair -> channels 2cp, 2cp+1
    const unsigned short* base = g1c + (size_t)chunk * N_NODES * 32;
    int s = rs[wid], e = rs[wid + 1];
    float a0x = 0.f, a0y = 0.f, a1x = 0.f, a1y = 0.f;
    int p = s;
    for (; p + 7 < e; p += 8) {
        int i0 = eidx[p + slot];
        int i1 = eidx[p + 4 + slot];
        unsigned int u0 = *(const unsigned int*)&base[(size_t)i0 * 32 + cp * 2];
        unsigned int u1 = *(const unsigned int*)&base[(size_t)i1 * 32 + cp * 2];
        a0x += lo2f(u0); a0y += hi2f(u0);
        a1x += lo2f(u1); a1y += hi2f(u1);
    }
    for (; p < e; p += 4) {
        bool ok = (p + slot) < e;
        int i0 = ok ? eidx[p + slot] : 0;
        unsigned int u0 = ok ? *(const unsigned int*)&base[(size_t)i0 * 32 + cp * 2] : 0u;
        a0x += lo2f(u0); a0y += hi2f(u0);
    }
    a0x += a1x; a0y += a1y;
    a0x += __shfl_xor(a0x, 32); a0y += __shfl_xor(a0y, 32);
    a0x += __shfl_xor(a0x, 16); a0y += __shfl_xor(a0y, 16);
    if (slot == 0) {
        unsigned int gi = *(const unsigned int*)&base[(size_t)wid * 32 + cp * 2];
        float d = dis[wid];
        float2 bv = *(const float2*)&b1[chunk * 32 + cp * 2];
        float zx = fmaf(d, a0x + lo2f(gi), bv.x);
        float zy = fmaf(d, a0y + hi2f(gi), bv.y);
        *(unsigned int*)&z1c[((size_t)chunk * N_NODES + wid) * 32 + cp * 2] = pack2(zx, zy);
    }
}

// layer 2: 4 chunks of 32 channels; XCDs 0..7 -> chunks 0,1,2,3,0,1,2,3; fp32 output row-major.
__global__ __launch_bounds__(256) void k_agg2(const unsigned short* __restrict__ g2c, const float* __restrict__ dis,
                                              const float* __restrict__ b2, const int* __restrict__ rs,
                                              const int* __restrict__ eidx, float* __restrict__ out) {
    int bx = blockIdx.x;
    int xcd = bx & 7;
    int chunk = xcd & 3;
    int sub = xcd >> 2;          // two XCD-groups split the node range per chunk
    int grp = bx >> 3;
    int t = threadIdx.x;
    int wave = t >> 6, lane = t & 63;
    int wid = (grp * 2 + sub) * 4 + wave;
    if (wid >= N_NODES) return;
    int slot = lane >> 4;
    int cp = lane & 15;
    const unsigned short* base = g2c + (size_t)chunk * N_NODES * 32;
    int s = rs[wid], e = rs[wid + 1];
    float a0x = 0.f, a0y = 0.f, a1x = 0.f, a1y = 0.f;
    int p = s;
    for (; p + 7 < e; p += 8) {
        int i0 = eidx[p + slot];
        int i1 = eidx[p + 4 + slot];
        unsigned int u0 = *(const unsigned int*)&base[(size_t)i0 * 32 + cp * 2];
        unsigned int u1 = *(const unsigned int*)&base[(size_t)i1 * 32 + cp * 2];
        a0x += lo2f(u0); a0y += hi2f(u0);
        a1x += lo2f(u1); a1y += hi2f(u1);
    }
    for (; p < e; p += 4) {
        bool ok = (p + slot) < e;
        int i0 = ok ? eidx[p + slot] : 0;
        unsigned int u0 = ok ? *(const unsigned int*)&base[(size_t)i0 * 32 + cp * 2] : 0u;
        a0x += lo2f(u0); a0y += hi2f(u0);
    }
    a0x += a1x; a0y += a1y;
    a0x += __shfl_xor(a0x, 32); a0y += __shfl_xor(a0y, 32);
    a0x += __shfl_xor(a0x, 16); a0y += __shfl_xor(a0y, 16);
    if (slot == 0) {
        unsigned int gi = *(const unsigned int*)&base[(size_t)wid * 32 + cp * 2];
        float d = dis[wid];
        float2 bv = *(const float2*)&b2[chunk * 32 + cp * 2];
        float2 o = make_float2(fmaf(d, a0x + lo2f(gi), bv.x), fmaf(d, a0y + hi2f(gi), bv.y));
        *(float2*)&out[(size_t)wid * C_OUT + chunk * 32 + cp * 2] = o;
    }
}

// ---------------- BN stats (reads chunked z1c) ----------------

#define BN_BLOCKS 256

__global__ __launch_bounds__(256) void k_bnstats(const unsigned short* __restrict__ z1c, float* __restrict__ bnsum,
                                                 float* __restrict__ bnsq) {
    __shared__ float redsum[4][256];
    __shared__ float redsq[4][256];
    int t = threadIdx.x;
    int wave = t >> 6, lane = t & 63;
    int gw = blockIdx.x * 4 + wave;
    const int W = BN_BLOCKS * 4;
    // lane handles channels c = lane*4..+3 -> chunk = lane>>3, offset (lane&7)*4
    size_t coff = (size_t)(lane >> 3) * N_NODES * 32 + (lane & 7) * 4;
    float s0 = 0.f, s1 = 0.f, s2 = 0.f, s3 = 0.f;
    float q0 = 0.f, q1 = 0.f, q2 = 0.f, q3 = 0.f;
    int r = gw;
    for (; r + W < N_NODES; r += 2 * W) {
        ushort4 va = *(const ushort4*)&z1c[coff + (size_t)r * 32];
        ushort4 vb = *(const ushort4*)&z1c[coff + (size_t)(r + W) * 32];
        float a0 = bf2f(va.x), a1 = bf2f(va.y), a2 = bf2f(va.z), a3 = bf2f(va.w);
        float b0 = bf2f(vb.x), b1 = bf2f(vb.y), b2 = bf2f(vb.z), b3 = bf2f(vb.w);
        s0 += a0 + b0; s1 += a1 + b1; s2 += a2 + b2; s3 += a3 + b3;
        q0 = fmaf(a0, a0, fmaf(b0, b0, q0));
        q1 = fmaf(a1, a1, fmaf(b1, b1, q1));
        q2 = fmaf(a2, a2, fmaf(b2, b2, q2));
        q3 = fmaf(a3, a3, fmaf(b3, b3, q3));
    }
    if (r < N_NODES) {
        ushort4 va = *(const ushort4*)&z1c[coff + (size_t)r * 32];
        float a0 = bf2f(va.x), a1 = bf2f(va.y), a2 = bf2f(va.z), a3 = bf2f(va.w);
        s0 += a0; s1 += a1; s2 += a2; s3 += a3;
        q0 = fmaf(a0, a0, q0); q1 = fmaf(a1, a1, q1);
        q2 = fmaf(a2, a2, q2); q3 = fmaf(a3, a3, q3);
    }
    redsum[wave][lane * 4 + 0] = s0; redsum[wave][lane * 4 + 1] = s1;
    redsum[wave][lane * 4 + 2] = s2; redsum[wave][lane * 4 + 3] = s3;
    redsq[wave][lane * 4 + 0] = q0; redsq[wave][lane * 4 + 1] = q1;
    redsq[wave][lane * 4 + 2] = q2; redsq[wave][lane * 4 + 3] = q3;
    __syncthreads();
    float ts = redsum[0][t] + redsum[1][t] + redsum[2][t] + redsum[3][t];
    float tq = redsq[0][t] + redsq[1][t] + redsq[2][t] + redsq[3][t];
    atomicAdd(&bnsum[t], ts);
    atomicAdd(&bnsq[t], tq);
}

__global__ void k_bnfinal(const float* __restrict__ bnsum, const float* __restrict__ bnsq,
                          const float* __restrict__ gamma, const float* __restrict__ beta,
                          float* __restrict__ a_c, float* __restrict__ b_c) {
    int c = threadIdx.x;
    float inv_n = 1.0f / (float)N_NODES;
    float mu = bnsum[c] * inv_n;
    float var = bnsq[c] * inv_n - mu * mu;
    float a = gamma[c] * rsqrtf(var + BN_EPS);
    a_c[c] = a;
    b_c[c] = beta[c] - mu * a;
}

// ---------------- launch ----------------

extern "C" void kernel_launch(void* const* d_in, const int* in_sizes, int n_in,
                              void* d_out, int out_size, void* d_ws, size_t ws_size,
                              hipStream_t stream) {
    const float* x      = (const float*)d_in[0];
    const int*   ei     = (const int*)d_in[1];
    const float* W1     = (const float*)d_in[2];
    const float* b1     = (const float*)d_in[3];
    const float* gamma1 = (const float*)d_in[4];
    const float* beta1  = (const float*)d_in[5];
    const float* W2     = (const float*)d_in[6];
    const float* b2     = (const float*)d_in[7];
    const int* srcv = ei;
    const int* dstv = ei + N_EDGES;
    float* out = (float*)d_out;

    char* w = (char*)d_ws;
    size_t off = 0;
    auto alloc = [&](size_t bytes) {
        void* p = w + off;
        off = (off + bytes + 255) & ~(size_t)255;
        return p;
    };
    int*   deg     = (int*)alloc(N_NODES * 4);
    float* dis     = (float*)alloc(N_NODES * 4);
    int*   rs      = (int*)alloc((N_NODES + 1) * 4);
    int*   cur     = (int*)alloc((N_NODES + 1) * 4);
    int*   partial = (int*)alloc(128 * 4);
    float* bnsum   = (float*)alloc(256 * 4);
    float* bnsq    = (float*)alloc(256 * 4);
    float* a_c     = (float*)alloc(256 * 4);
    float* b_c     = (float*)alloc(256 * 4);
    int*   eidx    = (int*)alloc((size_t)N_EDGES * 4);
    unsigned short* WT1 = (unsigned short*)alloc((size_t)C_IN * C_HID * 2);
    unsigned short* WT2 = (unsigned short*)alloc((size_t)C_HID * C_OUT * 2);
    unsigned short* g1c = (unsigned short*)alloc((size_t)N_NODES * C_HID * 2);
    unsigned short* z1c = (unsigned short*)alloc((size_t)N_NODES * C_HID * 2);
    unsigned short* g2c = (unsigned short*)alloc((size_t)N_NODES * C_OUT * 2);
    (void)ws_size; (void)in_sizes; (void)n_in; (void)out_size;

    hipMemsetAsync(deg, 0, N_NODES * 4, stream);
    hipMemsetAsync(bnsum, 0, 2048, stream);

    int nb = (N_NODES + 511) / 512;  // 98
    k_deg<<<(N_EDGES + 255) / 256, 256, 0, stream>>>(dstv, deg);
    k_scan1<<<nb, 512, 0, stream>>>(deg, rs, partial, dis);
    k_scan23<<<(N_NODES + 255) / 256, 256, 0, stream>>>(rs, partial, cur, nb);
    k_scatter<<<(N_EDGES + 255) / 256, 256, 0, stream>>>(srcv, dstv, cur, eidx);
    k_wtrans<<<(C_IN * C_HID + C_HID * C_OUT + 255) / 256, 256, 0, stream>>>(W1, W2, WT1, WT2);

    dim3 gg1((N_NODES + GBM - 1) / GBM, C_HID / GBM);
    k_gemm<false><<<gg1, 256, 0, stream>>>((const void*)x, WT1, g1c, dis, nullptr, nullptr,
                                           N_NODES, C_HID, C_IN);
    // agg1: 8 chunks x ceil(50000/4) node-groups
    k_agg1<<<((N_NODES + 3) / 4) * 8, 256, 0, stream>>>(g1c, dis, b1, rs, eidx, z1c);
    k_bnstats<<<BN_BLOCKS, 256, 0, stream>>>(z1c, bnsum, bnsq);
    k_bnfinal<<<1, 256, 0, stream>>>(bnsum, bnsq, gamma1, beta1, a_c, b_c);

    dim3 gg2((N_NODES + GBM - 1) / GBM, C_OUT / GBM);
    k_gemm<true><<<gg2, 256, 0, stream>>>((const void*)z1c, WT2, g2c, dis, a_c, b_c,
                                          N_NODES, C_OUT, C_HID);
    // agg2: 4 chunks x 2 sub-ranges x ceil(50000/8) groups
    k_agg2<<<((N_NODES + 7) / 8) * 8, 256, 0, stream>>>(g2c, dis, b2, rs, eidx, out);
}

// Round 7
// 305.938 us; speedup vs baseline: 1.4805x; 1.4805x over previous
//
#include <hip/hip_runtime.h>

#define N_NODES 50000
#define N_EDGES 800000
#define C_IN 128
#define C_HID 256
#define C_OUT 128
#define BN_EPS 1e-5f

typedef __bf16 v8bf __attribute__((ext_vector_type(8)));
typedef float f32x4 __attribute__((ext_vector_type(4)));

// ---------- bf16 helpers (round-to-nearest-even) ----------
static __device__ __forceinline__ unsigned short f2bf(float f) {
    unsigned int u = __float_as_uint(f);
    u += 0x7fffu + ((u >> 16) & 1u);
    return (unsigned short)(u >> 16);
}
static __device__ __forceinline__ float bf2f(unsigned short h) {
    return __uint_as_float((unsigned int)h << 16);
}
static __device__ __forceinline__ unsigned int pack2(float a, float b) {
    return (unsigned int)f2bf(a) | ((unsigned int)f2bf(b) << 16);
}
static __device__ __forceinline__ float lo2f(unsigned int u) { return __uint_as_float(u << 16); }
static __device__ __forceinline__ float hi2f(unsigned int u) { return __uint_as_float(u & 0xffff0000u); }

#define DEG_BLOCKS ((N_EDGES + 255) / 256)

// ---------------- degree + weight transpose (fused launch) ----------------

__global__ __launch_bounds__(256) void k_deg_wtrans(const int* __restrict__ dst, int* __restrict__ deg,
                                                    const float* __restrict__ W1, const float* __restrict__ W2,
                                                    unsigned short* __restrict__ WT1, unsigned short* __restrict__ WT2) {
    int bx = blockIdx.x, t = threadIdx.x;
    if (bx < DEG_BLOCKS) {
        int e = bx * 256 + t;
        if (e < N_EDGES) atomicAdd(&deg[dst[e]], 1);
    } else {
        int i = (bx - DEG_BLOCKS) * 256 + t;  // [0, 65536)
        if (i < C_IN * C_HID) {               // WT1[n][k] = W1[k][n], n<256, k<128
            int n = i >> 7, k = i & 127;
            WT1[n * C_IN + k] = f2bf(W1[k * C_HID + n]);
        } else {
            int j = i - C_IN * C_HID;         // WT2[n][k] = W2[k][n], n<128, k<256
            int n = j >> 8, k = j & 255;
            WT2[n * C_HID + k] = f2bf(W2[k * C_OUT + n]);
        }
    }
}

// ---------------- CSR build ----------------

__global__ __launch_bounds__(512) void k_scan1(const int* __restrict__ deg, int* __restrict__ rs,
                                               int* __restrict__ partial, float* __restrict__ dis) {
    __shared__ int s[512];
    int t = threadIdx.x;
    int i = blockIdx.x * 512 + t;
    int v = (i < N_NODES) ? deg[i] : 0;
    if (i < N_NODES) dis[i] = rsqrtf((float)v + 1.0f);
    s[t] = v;
    __syncthreads();
    for (int off = 1; off < 512; off <<= 1) {
        int tv = (t >= off) ? s[t - off] : 0;
        __syncthreads();
        s[t] += tv;
        __syncthreads();
    }
    if (i < N_NODES) rs[i + 1] = s[t];
    if (t == 511) partial[blockIdx.x] = s[511];
}

// fused scan2+scan3: each block locally re-scans the <=128 partials (L2-hot)
__global__ __launch_bounds__(256) void k_scan23(int* __restrict__ rs, const int* __restrict__ partial,
                                                int* __restrict__ cur, int nb) {
    __shared__ int pre[128];
    __shared__ int wsum[2];
    int t = threadIdx.x;
    int lane = t & 63;
    int pv = 0, v = 0;
    if (t < 128) {
        pv = (t < nb) ? partial[t] : 0;
        v = pv;
#pragma unroll
        for (int off = 1; off < 64; off <<= 1) {
            int u = __shfl_up(v, off);
            if (lane >= off) v += u;
        }
        if (lane == 63) wsum[t >> 6] = v;
    }
    __syncthreads();
    if (t < 128) {
        if (t >= 64) v += wsum[0];
        pre[t] = v - pv;
    }
    __syncthreads();
    int i = blockIdx.x * 256 + t;
    if (i < N_NODES) {
        int vv = rs[i + 1] + pre[i >> 9];
        rs[i + 1] = vv;
        cur[i + 1] = vv;
    }
    if (i == 0) { rs[0] = 0; cur[0] = 0; }
}

// ---------------- scatter + x-prescale (fused launch) ----------------
// xs[i] = bf16(dis[i] * x[i])  (128 ch, 800000 threads of 8ch each)

#define SCAT_BLOCKS ((N_EDGES + 255) / 256)

__global__ __launch_bounds__(256) void k_scatter_xscale(const int* __restrict__ src, const int* __restrict__ dst,
                                                        int* __restrict__ cur, int* __restrict__ eidx,
                                                        const float* __restrict__ x, const float* __restrict__ dis,
                                                        unsigned short* __restrict__ xs) {
    int bx = blockIdx.x, t = threadIdx.x;
    if (bx < SCAT_BLOCKS) {
        int e = bx * 256 + t;
        if (e < N_EDGES) {
            int pos = atomicAdd(&cur[dst[e]], 1);
            eidx[pos] = src[e];
        }
    } else {
        int i = (bx - SCAT_BLOCKS) * 256 + t;  // 16 groups of 8ch per node
        int node = i >> 4;
        if (node < N_NODES) {
            int g8 = (i & 15) * 8;
            float d = dis[node];
            float4 v0 = *(const float4*)&x[(size_t)node * C_IN + g8];
            float4 v1 = *(const float4*)&x[(size_t)node * C_IN + g8 + 4];
            uint4 o = make_uint4(pack2(v0.x * d, v0.y * d), pack2(v0.z * d, v0.w * d),
                                 pack2(v1.x * d, v1.y * d), pack2(v1.z * d, v1.w * d));
            *(uint4*)&xs[(size_t)node * C_IN + g8] = o;
        }
    }
}

// ---------------- 128-ch row aggregate: one wave per node, 2 edges/instr ----------------
// acc_i = sum_{src->i} g[src];  out = dis_i*(acc + g_i) (+bias, fp32 if FINAL else bf16)
// lane layout: slot=lane>>5 (edge parity), cp=lane&31 (channels cp*4..+3, ushort4=8B loads)

template <bool FINAL>
__global__ __launch_bounds__(256) void k_aggr(const unsigned short* __restrict__ g,
                                              const float* __restrict__ dis, const float* __restrict__ bias,
                                              const int* __restrict__ rs, const int* __restrict__ eidx,
                                              unsigned short* __restrict__ outb, float* __restrict__ outf) {
    int wid = (blockIdx.x * 256 + threadIdx.x) >> 6;
    int lane = threadIdx.x & 63;
    if (wid >= N_NODES) return;
    int slot = lane >> 5;
    int cp = lane & 31;
    int s = rs[wid], e = rs[wid + 1];
    float a0 = 0.f, a1 = 0.f, a2 = 0.f, a3 = 0.f;
    float c0 = 0.f, c1 = 0.f, c2 = 0.f, c3 = 0.f;
    int p = s;
    for (; p + 7 < e; p += 8) {  // 8 edges, 4 gathers in flight per lane
        int i0 = eidx[p + slot];
        int i1 = eidx[p + 2 + slot];
        int i2 = eidx[p + 4 + slot];
        int i3 = eidx[p + 6 + slot];
        ushort4 v0 = *(const ushort4*)&g[(size_t)i0 * 128 + cp * 4];
        ushort4 v1 = *(const ushort4*)&g[(size_t)i1 * 128 + cp * 4];
        ushort4 v2 = *(const ushort4*)&g[(size_t)i2 * 128 + cp * 4];
        ushort4 v3 = *(const ushort4*)&g[(size_t)i3 * 128 + cp * 4];
        a0 += bf2f(v0.x) + bf2f(v1.x); a1 += bf2f(v0.y) + bf2f(v1.y);
        a2 += bf2f(v0.z) + bf2f(v1.z); a3 += bf2f(v0.w) + bf2f(v1.w);
        c0 += bf2f(v2.x) + bf2f(v3.x); c1 += bf2f(v2.y) + bf2f(v3.y);
        c2 += bf2f(v2.z) + bf2f(v3.z); c3 += bf2f(v2.w) + bf2f(v3.w);
    }
    for (; p + 1 < e; p += 2) {
        int i0 = eidx[p + slot];
        ushort4 v0 = *(const ushort4*)&g[(size_t)i0 * 128 + cp * 4];
        a0 += bf2f(v0.x); a1 += bf2f(v0.y); a2 += bf2f(v0.z); a3 += bf2f(v0.w);
    }
    if (p < e && slot == 0) {  // odd remainder handled by slot 0
        int i0 = eidx[p];
        ushort4 v0 = *(const ushort4*)&g[(size_t)i0 * 128 + cp * 4];
        a0 += bf2f(v0.x); a1 += bf2f(v0.y); a2 += bf2f(v0.z); a3 += bf2f(v0.w);
    }
    a0 += c0; a1 += c1; a2 += c2; a3 += c3;
    a0 += __shfl_xor(a0, 32); a1 += __shfl_xor(a1, 32);
    a2 += __shfl_xor(a2, 32); a3 += __shfl_xor(a3, 32);
    if (slot == 0) {
        ushort4 gi = *(const ushort4*)&g[(size_t)wid * 128 + cp * 4];
        float d = dis[wid];
        if (FINAL) {
            float4 bv = *(const float4*)&bias[cp * 4];
            float4 o = make_float4(fmaf(d, a0 + bf2f(gi.x), bv.x), fmaf(d, a1 + bf2f(gi.y), bv.y),
                                   fmaf(d, a2 + bf2f(gi.z), bv.z), fmaf(d, a3 + bf2f(gi.w), bv.w));
            *(float4*)&outf[(size_t)wid * 128 + cp * 4] = o;
        } else {
            ushort4 z;
            z.x = f2bf(d * (a0 + bf2f(gi.x)));
            z.y = f2bf(d * (a1 + bf2f(gi.y)));
            z.z = f2bf(d * (a2 + bf2f(gi.z)));
            z.w = f2bf(d * (a3 + bf2f(gi.w)));
            *(ushort4*)&outb[(size_t)wid * 128 + cp * 4] = z;
        }
    }
}

// ---------------- MFMA bf16 GEMM ----------------
// TRANS=false (GEMM1): A=P bf16 plain, C = bf16( A@B + bias[col] )          K=128, N=256
// TRANS=true  (GEMM2): A=z1 bf16 with BN/ReLU (coeffs computed in-kernel from bnsum/bnsq),
//                      C = bf16( (A'@B) * dis[row] )                        K=256, N=128

#define GBM 128
#define GBK 64
#define LDA 72

template <bool TRANS>
__global__ __launch_bounds__(256) void k_gemm(const unsigned short* __restrict__ Ah,
                                              const unsigned short* __restrict__ BT,
                                              unsigned short* __restrict__ C,
                                              const float* __restrict__ dis, const float* __restrict__ bias,
                                              const float* __restrict__ bnsum, const float* __restrict__ bnsq,
                                              const float* __restrict__ gamma, const float* __restrict__ beta,
                                              int M, int N, int K) {
    __shared__ unsigned short Alds[GBM * LDA];
    __shared__ unsigned short Blds[GBM * LDA];
    __shared__ float ep_s[GBM];      // dis[row] (TRANS) or bias[col] (plain)
    __shared__ float tsc_s[256];
    __shared__ float tof_s[256];

    int t = threadIdx.x;
    int row0 = blockIdx.x * GBM;
    int col0 = blockIdx.y * GBM;
    int wave = t >> 6, lane = t & 63;
    int wm = wave & 1, wn = wave >> 1;
    int lm = lane & 15, quad = lane >> 4;

    if (TRANS) {
        if (t < GBM) ep_s[t] = (row0 + t < M) ? dis[row0 + t] : 0.f;
        // fused bnfinal: per-channel BN coeffs (K=256 channels, 256 threads)
        float inv_n = 1.0f / (float)N_NODES;
        float mu = bnsum[t] * inv_n;
        float var = bnsq[t] * inv_n - mu * mu;
        float a = gamma[t] * rsqrtf(var + BN_EPS);
        tsc_s[t] = a;
        tof_s[t] = beta[t] - mu * a;
    } else {
        if (t < GBM) ep_s[t] = bias[col0 + t];
    }
    __syncthreads();

    int sr = t >> 1;
    int kb = (t & 1) * 32;

    f32x4 acc[4][4] = {};

    for (int kt = 0; kt < K; kt += GBK) {
        uint4 sa[4], sb[4];
        int r = row0 + sr;
#pragma unroll
        for (int j = 0; j < 4; ++j) {
            int k = kt + kb + 8 * j;
            uint4 h = (r < M) ? *(const uint4*)&Ah[(size_t)r * K + k] : make_uint4(0u, 0u, 0u, 0u);
            if (TRANS) {
                float4 s0 = *(const float4*)&tsc_s[k];
                float4 s1 = *(const float4*)&tsc_s[k + 4];
                float4 o0 = *(const float4*)&tof_s[k];
                float4 o1 = *(const float4*)&tof_s[k + 4];
                float f0 = fmaxf(fmaf(lo2f(h.x), s0.x, o0.x), 0.f);
                float f1 = fmaxf(fmaf(hi2f(h.x), s0.y, o0.y), 0.f);
                float f2 = fmaxf(fmaf(lo2f(h.y), s0.z, o0.z), 0.f);
                float f3 = fmaxf(fmaf(hi2f(h.y), s0.w, o0.w), 0.f);
                float f4 = fmaxf(fmaf(lo2f(h.z), s1.x, o1.x), 0.f);
                float f5 = fmaxf(fmaf(hi2f(h.z), s1.y, o1.y), 0.f);
                float f6 = fmaxf(fmaf(lo2f(h.w), s1.z, o1.z), 0.f);
                float f7 = fmaxf(fmaf(hi2f(h.w), s1.w, o1.w), 0.f);
                sa[j] = make_uint4(pack2(f0, f1), pack2(f2, f3), pack2(f4, f5), pack2(f6, f7));
            } else {
                sa[j] = h;
            }
            sb[j] = *(const uint4*)&BT[(size_t)(col0 + sr) * K + k];
        }
        __syncthreads();
#pragma unroll
        for (int j = 0; j < 4; ++j) {
            *(uint4*)&Alds[sr * LDA + kb + 8 * j] = sa[j];
            *(uint4*)&Blds[sr * LDA + kb + 8 * j] = sb[j];
        }
        __syncthreads();
#pragma unroll
        for (int kc = 0; kc < 2; ++kc) {
            v8bf af[4], bfv[4];
#pragma unroll
            for (int im = 0; im < 4; ++im)
                af[im] = *(const v8bf*)&Alds[(wm * 64 + im * 16 + lm) * LDA + kc * 32 + quad * 8];
#pragma unroll
            for (int in = 0; in < 4; ++in)
                bfv[in] = *(const v8bf*)&Blds[(wn * 64 + in * 16 + lm) * LDA + kc * 32 + quad * 8];
#pragma unroll
            for (int im = 0; im < 4; ++im)
#pragma unroll
                for (int in = 0; in < 4; ++in)
                    acc[im][in] = __builtin_amdgcn_mfma_f32_16x16x32_bf16(af[im], bfv[in], acc[im][in], 0, 0, 0);
        }
    }
#pragma unroll
    for (int im = 0; im < 4; ++im) {
        int rb = wm * 64 + im * 16 + quad * 4;
#pragma unroll
        for (int in = 0; in < 4; ++in) {
            f32x4 c = acc[im][in];
            int colLoc = wn * 64 + in * 16 + lm;
            int col = col0 + colLoc;
#pragma unroll
            for (int q = 0; q < 4; ++q) {
                int row = row0 + rb + q;
                if (row < M) {
                    float val = TRANS ? c[q] * ep_s[rb + q] : c[q] + ep_s[colLoc];
                    C[(size_t)row * N + col] = f2bf(val);
                }
            }
        }
    }
}

// ---------------- BN stats over z1 (row-major, 512B rows) ----------------

#define BN_BLOCKS 256

__global__ __launch_bounds__(256) void k_bnstats(const unsigned short* __restrict__ z1, float* __restrict__ bnsum,
                                                 float* __restrict__ bnsq) {
    __shared__ float redsum[4][256];
    __shared__ float redsq[4][256];
    int t = threadIdx.x;
    int wave = t >> 6, lane = t & 63;
    int gw = blockIdx.x * 4 + wave;
    const int W = BN_BLOCKS * 4;
    float s0 = 0.f, s1 = 0.f, s2 = 0.f, s3 = 0.f;
    float q0 = 0.f, q1 = 0.f, q2 = 0.f, q3 = 0.f;
    int r = gw;
    for (; r + W < N_NODES; r += 2 * W) {
        ushort4 va = *(const ushort4*)&z1[(size_t)r * C_HID + lane * 4];
        ushort4 vb = *(const ushort4*)&z1[(size_t)(r + W) * C_HID + lane * 4];
        float a0 = bf2f(va.x), a1 = bf2f(va.y), a2 = bf2f(va.z), a3 = bf2f(va.w);
        float b0 = bf2f(vb.x), b1 = bf2f(vb.y), b2 = bf2f(vb.z), b3 = bf2f(vb.w);
        s0 += a0 + b0; s1 += a1 + b1; s2 += a2 + b2; s3 += a3 + b3;
        q0 = fmaf(a0, a0, fmaf(b0, b0, q0));
        q1 = fmaf(a1, a1, fmaf(b1, b1, q1));
        q2 = fmaf(a2, a2, fmaf(b2, b2, q2));
        q3 = fmaf(a3, a3, fmaf(b3, b3, q3));
    }
    if (r < N_NODES) {
        ushort4 va = *(const ushort4*)&z1[(size_t)r * C_HID + lane * 4];
        float a0 = bf2f(va.x), a1 = bf2f(va.y), a2 = bf2f(va.z), a3 = bf2f(va.w);
        s0 += a0; s1 += a1; s2 += a2; s3 += a3;
        q0 = fmaf(a0, a0, q0); q1 = fmaf(a1, a1, q1);
        q2 = fmaf(a2, a2, q2); q3 = fmaf(a3, a3, q3);
    }
    redsum[wave][lane * 4 + 0] = s0; redsum[wave][lane * 4 + 1] = s1;
    redsum[wave][lane * 4 + 2] = s2; redsum[wave][lane * 4 + 3] = s3;
    redsq[wave][lane * 4 + 0] = q0; redsq[wave][lane * 4 + 1] = q1;
    redsq[wave][lane * 4 + 2] = q2; redsq[wave][lane * 4 + 3] = q3;
    __syncthreads();
    float ts = redsum[0][t] + redsum[1][t] + redsum[2][t] + redsum[3][t];
    float tq = redsq[0][t] + redsq[1][t] + redsq[2][t] + redsq[3][t];
    atomicAdd(&bnsum[t], ts);
    atomicAdd(&bnsq[t], tq);
}

// ---------------- launch ----------------

extern "C" void kernel_launch(void* const* d_in, const int* in_sizes, int n_in,
                              void* d_out, int out_size, void* d_ws, size_t ws_size,
                              hipStream_t stream) {
    const float* x      = (const float*)d_in[0];
    const int*   ei     = (const int*)d_in[1];
    const float* W1     = (const float*)d_in[2];
    const float* b1     = (const float*)d_in[3];
    const float* gamma1 = (const float*)d_in[4];
    const float* beta1  = (const float*)d_in[5];
    const float* W2     = (const float*)d_in[6];
    const float* b2     = (const float*)d_in[7];
    const int* srcv = ei;
    const int* dstv = ei + N_EDGES;
    float* out = (float*)d_out;

    char* w = (char*)d_ws;
    size_t off = 0;
    auto alloc = [&](size_t bytes) {
        void* p = w + off;
        off = (off + bytes + 255) & ~(size_t)255;
        return p;
    };
    // deg, bnsum, bnsq contiguous -> single memset
    int*   deg     = (int*)alloc(N_NODES * 4);        // 200192 aligned
    float* bnsum   = (float*)alloc(256 * 4);
    float* bnsq    = (float*)alloc(256 * 4);
    size_t zero_bytes = off;                           // covers deg+bnsum+bnsq
    float* dis     = (float*)alloc(N_NODES * 4);
    int*   rs      = (int*)alloc((N_NODES + 1) * 4);
    int*   cur     = (int*)alloc((N_NODES + 1) * 4);
    int*   partial = (int*)alloc(128 * 4);
    int*   eidx    = (int*)alloc((size_t)N_EDGES * 4);
    unsigned short* WT1 = (unsigned short*)alloc((size_t)C_IN * C_HID * 2);
    unsigned short* WT2 = (unsigned short*)alloc((size_t)C_HID * C_OUT * 2);
    unsigned short* xs  = (unsigned short*)alloc((size_t)N_NODES * C_IN * 2);
    unsigned short* P   = (unsigned short*)alloc((size_t)N_NODES * C_IN * 2);
    unsigned short* z1  = (unsigned short*)alloc((size_t)N_NODES * C_HID * 2);
    unsigned short* g2  = (unsigned short*)alloc((size_t)N_NODES * C_OUT * 2);
    (void)ws_size; (void)in_sizes; (void)n_in; (void)out_size;

    hipMemsetAsync(deg, 0, zero_bytes, stream);

    int nb = (N_NODES + 511) / 512;  // 98
    k_deg_wtrans<<<DEG_BLOCKS + 256, 256, 0, stream>>>(dstv, deg, W1, W2, WT1, WT2);
    k_scan1<<<nb, 512, 0, stream>>>(deg, rs, partial, dis);
    k_scan23<<<(N_NODES + 255) / 256, 256, 0, stream>>>(rs, partial, cur, nb);
    k_scatter_xscale<<<SCAT_BLOCKS + (N_NODES * 16 + 255) / 256, 256, 0, stream>>>(
        srcv, dstv, cur, eidx, x, dis, xs);

    // layer 1 reassociated: P = Ahat @ X  (128-ch gather), then Z1 = P@W1 + b1
    k_aggr<false><<<(N_NODES * 64 + 255) / 256, 256, 0, stream>>>(xs, dis, nullptr, rs, eidx, P, nullptr);
    dim3 gg1((N_NODES + GBM - 1) / GBM, C_HID / GBM);
    k_gemm<false><<<gg1, 256, 0, stream>>>(P, WT1, z1, nullptr, b1, nullptr, nullptr, nullptr, nullptr,
                                           N_NODES, C_HID, C_IN);
    k_bnstats<<<BN_BLOCKS, 256, 0, stream>>>(z1, bnsum, bnsq);

    // layer 2: g2 = dis * (relu(BN(z1)) @ W2), then out = Ahat-gather + b2
    dim3 gg2((N_NODES + GBM - 1) / GBM, C_OUT / GBM);
    k_gemm<true><<<gg2, 256, 0, stream>>>(z1, WT2, g2, dis, nullptr, bnsum, bnsq, gamma1, beta1,
                                          N_NODES, C_OUT, C_HID);
    k_aggr<true><<<(N_NODES * 64 + 255) / 256, 256, 0, stream>>>(g2, dis, b2, rs, eidx, nullptr, out);
}

// Round 8
// 300.060 us; speedup vs baseline: 1.5095x; 1.0196x over previous
//
#include <hip/hip_runtime.h>

#define N_NODES 50000
#define N_EDGES 800000
#define C_IN 128
#define C_HID 256
#define C_OUT 128
#define BN_EPS 1e-5f

typedef __bf16 v8bf __attribute__((ext_vector_type(8)));
typedef float f32x4 __attribute__((ext_vector_type(4)));

// ---------- bf16 helpers (round-to-nearest-even) ----------
static __device__ __forceinline__ unsigned short f2bf(float f) {
    unsigned int u = __float_as_uint(f);
    u += 0x7fffu + ((u >> 16) & 1u);
    return (unsigned short)(u >> 16);
}
static __device__ __forceinline__ float bf2f(unsigned short h) {
    return __uint_as_float((unsigned int)h << 16);
}
static __device__ __forceinline__ unsigned int pack2(float a, float b) {
    return (unsigned int)f2bf(a) | ((unsigned int)f2bf(b) << 16);
}
static __device__ __forceinline__ float lo2f(unsigned int u) { return __uint_as_float(u << 16); }
static __device__ __forceinline__ float hi2f(unsigned int u) { return __uint_as_float(u & 0xffff0000u); }

#define DEG_BLOCKS ((N_EDGES + 255) / 256)

// ---------------- degree + weight transpose (fused launch) ----------------

__global__ __launch_bounds__(256) void k_deg_wtrans(const int* __restrict__ dst, int* __restrict__ deg,
                                                    const float* __restrict__ W1, const float* __restrict__ W2,
                                                    unsigned short* __restrict__ WT1, unsigned short* __restrict__ WT2) {
    int bx = blockIdx.x, t = threadIdx.x;
    if (bx < DEG_BLOCKS) {
        int e = bx * 256 + t;
        if (e < N_EDGES) atomicAdd(&deg[dst[e]], 1);
    } else {
        int i = (bx - DEG_BLOCKS) * 256 + t;  // [0, 65536)
        if (i < C_IN * C_HID) {               // WT1[n][k] = W1[k][n]
            int n = i >> 7, k = i & 127;
            WT1[n * C_IN + k] = f2bf(W1[k * C_HID + n]);
        } else {
            int j = i - C_IN * C_HID;         // WT2[n][k] = W2[k][n]
            int n = j >> 8, k = j & 255;
            WT2[n * C_HID + k] = f2bf(W2[k * C_OUT + n]);
        }
    }
}

// ---------------- CSR build ----------------

__global__ __launch_bounds__(512) void k_scan1(const int* __restrict__ deg, int* __restrict__ rs,
                                               int* __restrict__ partial, float* __restrict__ dis) {
    __shared__ int s[512];
    int t = threadIdx.x;
    int i = blockIdx.x * 512 + t;
    int v = (i < N_NODES) ? deg[i] : 0;
    if (i < N_NODES) dis[i] = rsqrtf((float)v + 1.0f);
    s[t] = v;
    __syncthreads();
    for (int off = 1; off < 512; off <<= 1) {
        int tv = (t >= off) ? s[t - off] : 0;
        __syncthreads();
        s[t] += tv;
        __syncthreads();
    }
    if (i < N_NODES) rs[i + 1] = s[t];
    if (t == 511) partial[blockIdx.x] = s[511];
}

// fused scan2+scan3
__global__ __launch_bounds__(256) void k_scan23(int* __restrict__ rs, const int* __restrict__ partial,
                                                int* __restrict__ cur, int nb) {
    __shared__ int pre[128];
    __shared__ int wsum[2];
    int t = threadIdx.x;
    int lane = t & 63;
    int pv = 0, v = 0;
    if (t < 128) {
        pv = (t < nb) ? partial[t] : 0;
        v = pv;
#pragma unroll
        for (int off = 1; off < 64; off <<= 1) {
            int u = __shfl_up(v, off);
            if (lane >= off) v += u;
        }
        if (lane == 63) wsum[t >> 6] = v;
    }
    __syncthreads();
    if (t < 128) {
        if (t >= 64) v += wsum[0];
        pre[t] = v - pv;
    }
    __syncthreads();
    int i = blockIdx.x * 256 + t;
    if (i < N_NODES) {
        int vv = rs[i + 1] + pre[i >> 9];
        rs[i + 1] = vv;
        cur[i + 1] = vv;
    }
    if (i == 0) { rs[0] = 0; cur[0] = 0; }
}

// ---------------- dst-sliced scatter + x-prescale (fused launch) ----------------
// Scatter: 8 dst-slices x 256 chunk-groups. slice = bx&7 rides the %8 XCD round-robin, so
// each 64B eidx line (one slice's nodes only) is written by ONE XCD -> fills in its L2
// before writeback (fixes the 16x write amplification of the unsliced scatter).

#define SCAT_GROUPS 256
#define NODES_PER_SLICE (N_NODES / 8)                     // 6250
#define EDGES_PER_CHUNK ((N_EDGES + SCAT_GROUPS - 1) / SCAT_GROUPS)  // 3125
#define SCAT_BLOCKS (SCAT_GROUPS * 8)                     // 2048

__global__ __launch_bounds__(256) void k_scatter_xscale(const int* __restrict__ src, const int* __restrict__ dst,
                                                        int* __restrict__ cur, int* __restrict__ eidx,
                                                        const float* __restrict__ x, const float* __restrict__ dis,
                                                        unsigned short* __restrict__ xs) {
    int bx = blockIdx.x, t = threadIdx.x;
    if (bx < SCAT_BLOCKS) {
        int slice = bx & 7;
        int g = bx >> 3;
        int lo = slice * NODES_PER_SLICE;
        int hi = lo + NODES_PER_SLICE;
        int e0 = g * EDGES_PER_CHUNK;
        int e1 = e0 + EDGES_PER_CHUNK;
        if (e1 > N_EDGES) e1 = N_EDGES;
        for (int e = e0 + t; e < e1; e += 256) {
            int d = dst[e];
            if (d >= lo && d < hi) {
                int pos = atomicAdd(&cur[d], 1);
                eidx[pos] = src[e];
            }
        }
    } else {
        int i = (bx - SCAT_BLOCKS) * 256 + t;  // 16 groups of 8ch per node
        int node = i >> 4;
        if (node < N_NODES) {
            int g8 = (i & 15) * 8;
            float d = dis[node];
            float4 v0 = *(const float4*)&x[(size_t)node * C_IN + g8];
            float4 v1 = *(const float4*)&x[(size_t)node * C_IN + g8 + 4];
            uint4 o = make_uint4(pack2(v0.x * d, v0.y * d), pack2(v0.z * d, v0.w * d),
                                 pack2(v1.x * d, v1.y * d), pack2(v1.z * d, v1.w * d));
            *(uint4*)&xs[(size_t)node * C_IN + g8] = o;
        }
    }
}

// ---------------- 128-ch row aggregate: one wave per node, 2 edges/instr ----------------

template <bool FINAL>
__global__ __launch_bounds__(256) void k_aggr(const unsigned short* __restrict__ g,
                                              const float* __restrict__ dis, const float* __restrict__ bias,
                                              const int* __restrict__ rs, const int* __restrict__ eidx,
                                              unsigned short* __restrict__ outb, float* __restrict__ outf) {
    int wid = (blockIdx.x * 256 + threadIdx.x) >> 6;
    int lane = threadIdx.x & 63;
    if (wid >= N_NODES) return;
    int slot = lane >> 5;
    int cp = lane & 31;
    int s = rs[wid], e = rs[wid + 1];
    float a0 = 0.f, a1 = 0.f, a2 = 0.f, a3 = 0.f;
    float c0 = 0.f, c1 = 0.f, c2 = 0.f, c3 = 0.f;
    int p = s;
    for (; p + 7 < e; p += 8) {
        int i0 = eidx[p + slot];
        int i1 = eidx[p + 2 + slot];
        int i2 = eidx[p + 4 + slot];
        int i3 = eidx[p + 6 + slot];
        ushort4 v0 = *(const ushort4*)&g[(size_t)i0 * 128 + cp * 4];
        ushort4 v1 = *(const ushort4*)&g[(size_t)i1 * 128 + cp * 4];
        ushort4 v2 = *(const ushort4*)&g[(size_t)i2 * 128 + cp * 4];
        ushort4 v3 = *(const ushort4*)&g[(size_t)i3 * 128 + cp * 4];
        a0 += bf2f(v0.x) + bf2f(v1.x); a1 += bf2f(v0.y) + bf2f(v1.y);
        a2 += bf2f(v0.z) + bf2f(v1.z); a3 += bf2f(v0.w) + bf2f(v1.w);
        c0 += bf2f(v2.x) + bf2f(v3.x); c1 += bf2f(v2.y) + bf2f(v3.y);
        c2 += bf2f(v2.z) + bf2f(v3.z); c3 += bf2f(v2.w) + bf2f(v3.w);
    }
    for (; p + 1 < e; p += 2) {
        int i0 = eidx[p + slot];
        ushort4 v0 = *(const ushort4*)&g[(size_t)i0 * 128 + cp * 4];
        a0 += bf2f(v0.x); a1 += bf2f(v0.y); a2 += bf2f(v0.z); a3 += bf2f(v0.w);
    }
    if (p < e && slot == 0) {
        int i0 = eidx[p];
        ushort4 v0 = *(const ushort4*)&g[(size_t)i0 * 128 + cp * 4];
        a0 += bf2f(v0.x); a1 += bf2f(v0.y); a2 += bf2f(v0.z); a3 += bf2f(v0.w);
    }
    a0 += c0; a1 += c1; a2 += c2; a3 += c3;
    a0 += __shfl_xor(a0, 32); a1 += __shfl_xor(a1, 32);
    a2 += __shfl_xor(a2, 32); a3 += __shfl_xor(a3, 32);
    if (slot == 0) {
        ushort4 gi = *(const ushort4*)&g[(size_t)wid * 128 + cp * 4];
        float d = dis[wid];
        if (FINAL) {
            float4 bv = *(const float4*)&bias[cp * 4];
            float4 o = make_float4(fmaf(d, a0 + bf2f(gi.x), bv.x), fmaf(d, a1 + bf2f(gi.y), bv.y),
                                   fmaf(d, a2 + bf2f(gi.z), bv.z), fmaf(d, a3 + bf2f(gi.w), bv.w));
            *(float4*)&outf[(size_t)wid * 128 + cp * 4] = o;
        } else {
            ushort4 z;
            z.x = f2bf(d * (a0 + bf2f(gi.x)));
            z.y = f2bf(d * (a1 + bf2f(gi.y)));
            z.z = f2bf(d * (a2 + bf2f(gi.z)));
            z.w = f2bf(d * (a3 + bf2f(gi.w)));
            *(ushort4*)&outb[(size_t)wid * 128 + cp * 4] = z;
        }
    }
}

// ---------------- MFMA bf16 GEMM ----------------
// TRANS=false (GEMM1): C = bf16( A@B + bias[col] ); ALSO accumulates BN stats (sum, sumsq of
//   the rounded bf16 outputs) per column into bnsum/bnsq via tile reduce + atomics.
// TRANS=true  (GEMM2): A with BN/ReLU (coeffs from bnsum/bnsq in-kernel), C = bf16((A'@B)*dis[row])

#define GBM 128
#define GBK 64
#define LDA 72

template <bool TRANS>
__global__ __launch_bounds__(256) void k_gemm(const unsigned short* __restrict__ Ah,
                                              const unsigned short* __restrict__ BT,
                                              unsigned short* __restrict__ C,
                                              const float* __restrict__ dis, const float* __restrict__ bias,
                                              float* __restrict__ bnsum, float* __restrict__ bnsq,
                                              const float* __restrict__ gamma, const float* __restrict__ beta,
                                              int M, int N, int K) {
    __shared__ unsigned short Alds[GBM * LDA];
    __shared__ unsigned short Blds[GBM * LDA];
    __shared__ float ep_s[GBM];
    __shared__ float tsc_s[256];
    __shared__ float tof_s[256];
    __shared__ float bnS[128];
    __shared__ float bnQ[128];

    int t = threadIdx.x;
    int row0 = blockIdx.x * GBM;
    int col0 = blockIdx.y * GBM;
    int wave = t >> 6, lane = t & 63;
    int wm = wave & 1, wn = wave >> 1;
    int lm = lane & 15, quad = lane >> 4;

    if (TRANS) {
        if (t < GBM) ep_s[t] = (row0 + t < M) ? dis[row0 + t] : 0.f;
        float inv_n = 1.0f / (float)N_NODES;
        float mu = bnsum[t] * inv_n;
        float var = bnsq[t] * inv_n - mu * mu;
        float a = gamma[t] * rsqrtf(var + BN_EPS);
        tsc_s[t] = a;
        tof_s[t] = beta[t] - mu * a;
    } else {
        if (t < GBM) { ep_s[t] = bias[col0 + t]; bnS[t] = 0.f; bnQ[t] = 0.f; }
    }
    __syncthreads();

    int sr = t >> 1;
    int kb = (t & 1) * 32;

    f32x4 acc[4][4] = {};

    for (int kt = 0; kt < K; kt += GBK) {
        uint4 sa[4], sb[4];
        int r = row0 + sr;
#pragma unroll
        for (int j = 0; j < 4; ++j) {
            int k = kt + kb + 8 * j;
            uint4 h = (r < M) ? *(const uint4*)&Ah[(size_t)r * K + k] : make_uint4(0u, 0u, 0u, 0u);
            if (TRANS) {
                float4 s0 = *(const float4*)&tsc_s[k];
                float4 s1 = *(const float4*)&tsc_s[k + 4];
                float4 o0 = *(const float4*)&tof_s[k];
                float4 o1 = *(const float4*)&tof_s[k + 4];
                float f0 = fmaxf(fmaf(lo2f(h.x), s0.x, o0.x), 0.f);
                float f1 = fmaxf(fmaf(hi2f(h.x), s0.y, o0.y), 0.f);
                float f2 = fmaxf(fmaf(lo2f(h.y), s0.z, o0.z), 0.f);
                float f3 = fmaxf(fmaf(hi2f(h.y), s0.w, o0.w), 0.f);
                float f4 = fmaxf(fmaf(lo2f(h.z), s1.x, o1.x), 0.f);
                float f5 = fmaxf(fmaf(hi2f(h.z), s1.y, o1.y), 0.f);
                float f6 = fmaxf(fmaf(lo2f(h.w), s1.z, o1.z), 0.f);
                float f7 = fmaxf(fmaf(hi2f(h.w), s1.w, o1.w), 0.f);
                sa[j] = make_uint4(pack2(f0, f1), pack2(f2, f3), pack2(f4, f5), pack2(f6, f7));
            } else {
                sa[j] = h;
            }
            sb[j] = *(const uint4*)&BT[(size_t)(col0 + sr) * K + k];
        }
        __syncthreads();
#pragma unroll
        for (int j = 0; j < 4; ++j) {
            *(uint4*)&Alds[sr * LDA + kb + 8 * j] = sa[j];
            *(uint4*)&Blds[sr * LDA + kb + 8 * j] = sb[j];
        }
        __syncthreads();
#pragma unroll
        for (int kc = 0; kc < 2; ++kc) {
            v8bf af[4], bfv[4];
#pragma unroll
            for (int im = 0; im < 4; ++im)
                af[im] = *(const v8bf*)&Alds[(wm * 64 + im * 16 + lm) * LDA + kc * 32 + quad * 8];
#pragma unroll
            for (int in = 0; in < 4; ++in)
                bfv[in] = *(const v8bf*)&Blds[(wn * 64 + in * 16 + lm) * LDA + kc * 32 + quad * 8];
#pragma unroll
            for (int im = 0; im < 4; ++im)
#pragma unroll
                for (int in = 0; in < 4; ++in)
                    acc[im][in] = __builtin_amdgcn_mfma_f32_16x16x32_bf16(af[im], bfv[in], acc[im][in], 0, 0, 0);
        }
    }

    float bs[4] = {0.f, 0.f, 0.f, 0.f}, bq[4] = {0.f, 0.f, 0.f, 0.f};
#pragma unroll
    for (int im = 0; im < 4; ++im) {
        int rb = wm * 64 + im * 16 + quad * 4;
#pragma unroll
        for (int in = 0; in < 4; ++in) {
            f32x4 c = acc[im][in];
            int colLoc = wn * 64 + in * 16 + lm;
            int col = col0 + colLoc;
#pragma unroll
            for (int q = 0; q < 4; ++q) {
                int row = row0 + rb + q;
                if (row < M) {
                    if (TRANS) {
                        C[(size_t)row * N + col] = f2bf(c[q] * ep_s[rb + q]);
                    } else {
                        unsigned short hb = f2bf(c[q] + ep_s[colLoc]);
                        C[(size_t)row * N + col] = hb;
                        float v = bf2f(hb);
                        bs[in] += v;
                        bq[in] = fmaf(v, v, bq[in]);
                    }
                }
            }
        }
    }
    if (!TRANS) {
        // reduce per-column stats across the 4 quads, stash per-wave in LDS, then global atomics
#pragma unroll
        for (int in = 0; in < 4; ++in) {
            float s = bs[in], q2 = bq[in];
            s += __shfl_xor(s, 16); q2 += __shfl_xor(q2, 16);
            s += __shfl_xor(s, 32); q2 += __shfl_xor(q2, 32);
            if (quad == 0) {
                atomicAdd(&bnS[wn * 64 + in * 16 + lm], s);
                atomicAdd(&bnQ[wn * 64 + in * 16 + lm], q2);
            }
        }
        __syncthreads();
        if (t < 128) {
            atomicAdd(&bnsum[col0 + t], bnS[t]);
            atomicAdd(&bnsq[col0 + t], bnQ[t]);
        }
    }
}

// ---------------- launch ----------------

extern "C" void kernel_launch(void* const* d_in, const int* in_sizes, int n_in,
                              void* d_out, int out_size, void* d_ws, size_t ws_size,
                              hipStream_t stream) {
    const float* x      = (const float*)d_in[0];
    const int*   ei     = (const int*)d_in[1];
    const float* W1     = (const float*)d_in[2];
    const float* b1     = (const float*)d_in[3];
    const float* gamma1 = (const float*)d_in[4];
    const float* beta1  = (const float*)d_in[5];
    const float* W2     = (const float*)d_in[6];
    const float* b2     = (const float*)d_in[7];
    const int* srcv = ei;
    const int* dstv = ei + N_EDGES;
    float* out = (float*)d_out;

    char* w = (char*)d_ws;
    size_t off = 0;
    auto alloc = [&](size_t bytes) {
        void* p = w + off;
        off = (off + bytes + 255) & ~(size_t)255;
        return p;
    };
    int*   deg     = (int*)alloc(N_NODES * 4);
    float* bnsum   = (float*)alloc(256 * 4);
    float* bnsq    = (float*)alloc(256 * 4);
    size_t zero_bytes = off;                           // deg + bnsum + bnsq
    float* dis     = (float*)alloc(N_NODES * 4);
    int*   rs      = (int*)alloc((N_NODES + 1) * 4);
    int*   cur     = (int*)alloc((N_NODES + 1) * 4);
    int*   partial = (int*)alloc(128 * 4);
    int*   eidx    = (int*)alloc((size_t)N_EDGES * 4);
    unsigned short* WT1 = (unsigned short*)alloc((size_t)C_IN * C_HID * 2);
    unsigned short* WT2 = (unsigned short*)alloc((size_t)C_HID * C_OUT * 2);
    unsigned short* xs  = (unsigned short*)alloc((size_t)N_NODES * C_IN * 2);
    unsigned short* P   = (unsigned short*)alloc((size_t)N_NODES * C_IN * 2);
    unsigned short* z1  = (unsigned short*)alloc((size_t)N_NODES * C_HID * 2);
    unsigned short* g2  = (unsigned short*)alloc((size_t)N_NODES * C_OUT * 2);
    (void)ws_size; (void)in_sizes; (void)n_in; (void)out_size;

    hipMemsetAsync(deg, 0, zero_bytes, stream);

    int nb = (N_NODES + 511) / 512;  // 98
    k_deg_wtrans<<<DEG_BLOCKS + 256, 256, 0, stream>>>(dstv, deg, W1, W2, WT1, WT2);
    k_scan1<<<nb, 512, 0, stream>>>(deg, rs, partial, dis);
    k_scan23<<<(N_NODES + 255) / 256, 256, 0, stream>>>(rs, partial, cur, nb);
    k_scatter_xscale<<<SCAT_BLOCKS + (N_NODES * 16 + 255) / 256, 256, 0, stream>>>(
        srcv, dstv, cur, eidx, x, dis, xs);

    // layer 1 reassociated: P = Ahat @ X, then Z1 = P@W1 + b1 (+ fused BN stats)
    k_aggr<false><<<(N_NODES * 64 + 255) / 256, 256, 0, stream>>>(xs, dis, nullptr, rs, eidx, P, nullptr);
    dim3 gg1((N_NODES + GBM - 1) / GBM, C_HID / GBM);
    k_gemm<false><<<gg1, 256, 0, stream>>>(P, WT1, z1, nullptr, b1, bnsum, bnsq, nullptr, nullptr,
                                           N_NODES, C_HID, C_IN);

    // layer 2: g2 = dis * (relu(BN(z1)) @ W2), then out = Ahat-gather + b2
    dim3 gg2((N_NODES + GBM - 1) / GBM, C_OUT / GBM);
    k_gemm<true><<<gg2, 256, 0, stream>>>(z1, WT2, g2, dis, nullptr, bnsum, bnsq, gamma1, beta1,
                                          N_NODES, C_OUT, C_HID);
    k_aggr<true><<<(N_NODES * 64 + 255) / 256, 256, 0, stream>>>(g2, dis, b2, rs, eidx, nullptr, out);
}